// Round 5
// baseline (662.841 us; speedup 1.0000x reference)
//
#include <hip/hip_runtime.h>
#include <math.h>

#define NFEAT 128

// edge record: .x = col index (int), .y = dis[src]*w (float bits); dis[dst] folded into epilogue
typedef int2 EdgeRec;

// ---------------- CSR build ----------------

__global__ void k_init(unsigned long long* packed, int N) {
  int i = blockIdx.x * blockDim.x + threadIdx.x;
  if (i < N) packed[i] = 0ull;
}

// ONE u64 atomic per edge: count in bits[40..], fixed-point (2^-32) weight sum in bits[0..40).
// Returned old count = this edge's slot offset within its row.
__global__ void k_count64(const int* __restrict__ dst, const float* __restrict__ ew,
                          unsigned long long* packed, int* off, int E) {
  int e = blockIdx.x * blockDim.x + threadIdx.x;
  if (e < E) {
    unsigned long long add = (1ull << 40) | (unsigned long long)(ew[e] * 4294967296.0f);
    unsigned long long old = atomicAdd(&packed[dst[e]], add);
    off[e] = (int)(old >> 40);
  }
}

__global__ void k_dis(const unsigned long long* __restrict__ packed, float* dis, int N) {
  int i = blockIdx.x * blockDim.x + threadIdx.x;
  if (i < N) {
    double s = (double)(packed[i] & ((1ull << 40) - 1)) * 2.3283064365386963e-10;  // /2^32
    float dg = 1.0f + (float)s;  // + self-loop weight
    dis[i] = 1.0f / sqrtf(dg);
  }
}

// ---- 3-phase parallel exclusive scan of (cnt[i]+1) -> rowptr, 1024 elems/block ----

__global__ __launch_bounds__(256) void k_scan1(const unsigned long long* __restrict__ packed,
                                               int* bsum, int N) {
  __shared__ int ls[256];
  int b = blockIdx.x, t = threadIdx.x;
  int base = b * 1024 + t * 4;
  int s = 0;
#pragma unroll
  for (int j = 0; j < 4; j++) { int i = base + j; if (i < N) s += (int)(packed[i] >> 40) + 1; }
  ls[t] = s;
  __syncthreads();
  for (int off = 128; off > 0; off >>= 1) {
    if (t < off) ls[t] += ls[t + off];
    __syncthreads();
  }
  if (t == 0) bsum[b] = ls[0];
}

__global__ __launch_bounds__(1024) void k_scan2(int* bsum, int SB) {
  __shared__ int ls[1024];
  int t = threadIdx.x;
  int v = (t < SB) ? bsum[t] : 0;
  ls[t] = v;
  __syncthreads();
  for (int off = 1; off < 1024; off <<= 1) {
    int u = (t >= off) ? ls[t - off] : 0;
    __syncthreads();
    ls[t] += u;
    __syncthreads();
  }
  if (t < SB) bsum[t] = ls[t] - v;  // exclusive
}

__global__ __launch_bounds__(256) void k_scan3(const unsigned long long* __restrict__ packed,
                                               const int* __restrict__ bsum,
                                               int* rowptr, int N, int M) {
  __shared__ int ls[256];
  int b = blockIdx.x, t = threadIdx.x;
  int base = b * 1024 + t * 4;
  int v[4]; int s = 0;
#pragma unroll
  for (int j = 0; j < 4; j++) {
    int i = base + j;
    v[j] = (i < N) ? (int)(packed[i] >> 40) + 1 : 0;
    s += v[j];
  }
  ls[t] = s;
  __syncthreads();
  for (int off = 1; off < 256; off <<= 1) {
    int u = (t >= off) ? ls[t - off] : 0;
    __syncthreads();
    ls[t] += u;
    __syncthreads();
  }
  int run = bsum[b] + ls[t] - s;
#pragma unroll
  for (int j = 0; j < 4; j++) { int i = base + j; if (i < N) { rowptr[i] = run; run += v[j]; } }
  if (b == 0 && t == 0) rowptr[N] = M;
}

__global__ void k_selfloop(const int* __restrict__ rowptr, const float* __restrict__ dis,
                           EdgeRec* ep, int N) {
  int i = blockIdx.x * blockDim.x + threadIdx.x;
  if (i < N) {
    EdgeRec r; r.x = i; r.y = __float_as_int(dis[i]);  // dis[i]*1.0; *dis[i] applied in epilogue
    ep[rowptr[i]] = r;
  }
}

// no atomics: slot = rowptr[dst] + 1 + off[e]
__global__ void k_fill(const int* __restrict__ src, const int* __restrict__ dst,
                       const float* __restrict__ ew, const float* __restrict__ dis,
                       const int* __restrict__ rowptr, const int* __restrict__ off,
                       EdgeRec* ep, int E) {
  int e = blockIdx.x * blockDim.x + threadIdx.x;
  if (e < E) {
    int s = src[e], d = dst[e];
    int p = rowptr[d] + 1 + off[e];
    EdgeRec r; r.x = s; r.y = __float_as_int(dis[s] * ew[e]);
    ep[p] = r;
  }
}

// ---------------- dense GEMM: Y[N,128] = X[N,128] @ W[128,128] ----------------
// 512-thread blocks (8 waves), W fully resident in 64 KB LDS -> 2 blocks/CU = 4 waves/SIMD.
// 8 rows/wave via wave-uniform broadcast loads, explicit register double-buffer.

__global__ __launch_bounds__(512) void k_gemm128(const float* __restrict__ X,
                                                 const float* __restrict__ W,
                                                 float* __restrict__ Y,
                                                 int N, int numTiles) {
  __shared__ float sW[128 * 128];  // 64 KB -> 2 blocks/CU
  int t = threadIdx.x;
  int wave = __builtin_amdgcn_readfirstlane(t >> 6);  // 0..7
  int lane = t & 63;
  {
    const float4* W4 = (const float4*)W;
    float4* sW4 = (float4*)sW;
    for (int i = t; i < 4096; i += 512) sW4[i] = W4[i];
  }
  __syncthreads();

  for (int tile = blockIdx.x; tile < numTiles; tile += gridDim.x) {
    int rowBase = tile * 64 + wave * 8;
    const float* xb[8];
#pragma unroll
    for (int r = 0; r < 8; r++) {
      int row = rowBase + r;
      if (row >= N) row = 0;
      xb[r] = X + (size_t)row * 128;
    }
    float2 acc[8];
#pragma unroll
    for (int r = 0; r < 8; r++) acc[r] = make_float2(0.f, 0.f);

    float4 cur[8], nxt[8];
#pragma unroll
    for (int r = 0; r < 8; r++) cur[r] = *(const float4*)(xb[r]);

    for (int k = 0; k < 128; k += 4) {
      if (k + 4 < 128) {
#pragma unroll
        for (int r = 0; r < 8; r++) nxt[r] = *(const float4*)(xb[r] + k + 4);
      }
#pragma unroll
      for (int kk = 0; kk < 4; kk++) {
        float2 wv = *(const float2*)(sW + (k + kk) * 128 + 2 * lane);
#pragma unroll
        for (int r = 0; r < 8; r++) {
          float xs = (&cur[r].x)[kk];
          acc[r].x = fmaf(xs, wv.x, acc[r].x);
          acc[r].y = fmaf(xs, wv.y, acc[r].y);
        }
      }
#pragma unroll
      for (int r = 0; r < 8; r++) cur[r] = nxt[r];
    }
#pragma unroll
    for (int r = 0; r < 8; r++) {
      int row = rowBase + r;
      if (row < N)
        *(float2*)(Y + (size_t)row * 128 + 2 * lane) = acc[r];
    }
  }
}

// ---------------- sparse aggregate, 128-wide: Out = relu(dis[n]*agg + b) ----------------
// One wave per dst node. Half-wave split: lanes 0-31 take even edge slots, 32-63 odd.
// Lane gathers float4 (features 4*l32..+3). 4 gather instrs per iter = 8 edges, ep
// records for the NEXT group prefetched during the current group's gathers.

__global__ __launch_bounds__(256) void k_agg128(const float* __restrict__ H,
                                                const int* __restrict__ rowptr,
                                                const EdgeRec* __restrict__ ep,
                                                const float* __restrict__ dis,
                                                const float* __restrict__ bias,
                                                float* __restrict__ Out, int N) {
  int wave = __builtin_amdgcn_readfirstlane(threadIdx.x >> 6);
  int lane = threadIdx.x & 63;
  int half = lane >> 5;
  int l32  = lane & 31;
  int node = blockIdx.x * 4 + wave;
  if (node >= N) return;
  int beg = rowptr[node], end = rowptr[node + 1];
  int last = end - 1;
  int pmax = (end - beg + 1) >> 1;  // pair-slots; slot p covers edge beg+2p+half
  int ebase = beg + half;

  float4 acc = make_float4(0.f, 0.f, 0.f, 0.f);
  EdgeRec cur[4], nxt[4];
#pragma unroll
  for (int j = 0; j < 4; j++) {
    int e = ebase + 2 * j;
    cur[j] = ep[e <= last ? e : last];
  }
  for (int p = 0; p < pmax; p += 4) {
    int nbase = ebase + 2 * (p + 4);
#pragma unroll
    for (int j = 0; j < 4; j++) {
      int e = nbase + 2 * j;
      nxt[j] = ep[e <= last ? e : last];
    }
    float4 h[4];
#pragma unroll
    for (int j = 0; j < 4; j++)
      h[j] = *(const float4*)(H + (size_t)cur[j].x * 128 + 4 * l32);
#pragma unroll
    for (int j = 0; j < 4; j++) {
      int e = ebase + 2 * (p + j);
      float w = (e <= last) ? __int_as_float(cur[j].y) : 0.f;
      acc.x = fmaf(w, h[j].x, acc.x);
      acc.y = fmaf(w, h[j].y, acc.y);
      acc.z = fmaf(w, h[j].z, acc.z);
      acc.w = fmaf(w, h[j].w, acc.w);
    }
#pragma unroll
    for (int j = 0; j < 4; j++) cur[j] = nxt[j];
  }
  // combine halves
  acc.x += __shfl_xor(acc.x, 32, 64);
  acc.y += __shfl_xor(acc.y, 32, 64);
  acc.z += __shfl_xor(acc.z, 32, 64);
  acc.w += __shfl_xor(acc.w, 32, 64);
  if (half == 0) {
    float ds = dis[node];
    float4 bv = *(const float4*)(bias + 4 * l32);
    float4 o;
    o.x = fmaf(ds, acc.x, bv.x); o.x = o.x > 0.f ? o.x : 0.f;
    o.y = fmaf(ds, acc.y, bv.y); o.y = o.y > 0.f ? o.y : 0.f;
    o.z = fmaf(ds, acc.z, bv.z); o.z = o.z > 0.f ? o.z : 0.f;
    o.w = fmaf(ds, acc.w, bv.w); o.w = o.w > 0.f ? o.w : 0.f;
    *(float4*)(Out + (size_t)node * 128 + 4 * l32) = o;
  }
}

// ---- layer-2 aggregate fused with W3 dot: z[node] = relu(dis*agg + b2) . W3 ----

__global__ __launch_bounds__(256) void k_agg_final(const float* __restrict__ H,
                                                   const int* __restrict__ rowptr,
                                                   const EdgeRec* __restrict__ ep,
                                                   const float* __restrict__ dis,
                                                   const float* __restrict__ bias,
                                                   const float* __restrict__ W3,
                                                   float* __restrict__ z, int N) {
  int wave = __builtin_amdgcn_readfirstlane(threadIdx.x >> 6);
  int lane = threadIdx.x & 63;
  int half = lane >> 5;
  int l32  = lane & 31;
  int node = blockIdx.x * 4 + wave;
  if (node >= N) return;
  int beg = rowptr[node], end = rowptr[node + 1];
  int last = end - 1;
  int pmax = (end - beg + 1) >> 1;
  int ebase = beg + half;

  float4 acc = make_float4(0.f, 0.f, 0.f, 0.f);
  EdgeRec cur[4], nxt[4];
#pragma unroll
  for (int j = 0; j < 4; j++) {
    int e = ebase + 2 * j;
    cur[j] = ep[e <= last ? e : last];
  }
  for (int p = 0; p < pmax; p += 4) {
    int nbase = ebase + 2 * (p + 4);
#pragma unroll
    for (int j = 0; j < 4; j++) {
      int e = nbase + 2 * j;
      nxt[j] = ep[e <= last ? e : last];
    }
    float4 h[4];
#pragma unroll
    for (int j = 0; j < 4; j++)
      h[j] = *(const float4*)(H + (size_t)cur[j].x * 128 + 4 * l32);
#pragma unroll
    for (int j = 0; j < 4; j++) {
      int e = ebase + 2 * (p + j);
      float w = (e <= last) ? __int_as_float(cur[j].y) : 0.f;
      acc.x = fmaf(w, h[j].x, acc.x);
      acc.y = fmaf(w, h[j].y, acc.y);
      acc.z = fmaf(w, h[j].z, acc.z);
      acc.w = fmaf(w, h[j].w, acc.w);
    }
#pragma unroll
    for (int j = 0; j < 4; j++) cur[j] = nxt[j];
  }
  acc.x += __shfl_xor(acc.x, 32, 64);
  acc.y += __shfl_xor(acc.y, 32, 64);
  acc.z += __shfl_xor(acc.z, 32, 64);
  acc.w += __shfl_xor(acc.w, 32, 64);
  // both halves now identical; compute o and partial dot in all 64 lanes
  float ds = dis[node];
  float4 bv = *(const float4*)(bias + 4 * l32);
  float4 w3v = *(const float4*)(W3 + 4 * l32);
  float o, pdot = 0.f;
  o = fmaf(ds, acc.x, bv.x); o = o > 0.f ? o : 0.f; pdot = fmaf(o, w3v.x, pdot);
  o = fmaf(ds, acc.y, bv.y); o = o > 0.f ? o : 0.f; pdot = fmaf(o, w3v.y, pdot);
  o = fmaf(ds, acc.z, bv.z); o = o > 0.f ? o : 0.f; pdot = fmaf(o, w3v.z, pdot);
  o = fmaf(ds, acc.w, bv.w); o = o > 0.f ? o : 0.f; pdot = fmaf(o, w3v.w, pdot);
  // 64-lane reduce double-counts (halves identical) -> scale by 0.5
#pragma unroll
  for (int off = 32; off > 0; off >>= 1) pdot += __shfl_down(pdot, off, 64);
  if (lane == 0) z[node] = 0.5f * pdot;
}

// ---------------- scalar aggregate + bias + relu ----------------

__global__ void k_aggs(const float* __restrict__ z, const int* __restrict__ rowptr,
                       const EdgeRec* __restrict__ ep, const float* __restrict__ dis,
                       const float* __restrict__ b3, float* __restrict__ out, int N) {
  int n = blockIdx.x * blockDim.x + threadIdx.x;
  if (n >= N) return;
  float acc = 0.f;
  int end = rowptr[n + 1];
  for (int e = rowptr[n]; e < end; e++) {
    EdgeRec p = ep[e];
    acc = fmaf(__int_as_float(p.y), z[p.x], acc);
  }
  acc = fmaf(dis[n], acc, b3[0]);
  out[n] = acc > 0.f ? acc : 0.f;
}

// ---------------- launch ----------------

extern "C" void kernel_launch(void* const* d_in, const int* in_sizes, int n_in,
                              void* d_out, int out_size, void* d_ws, size_t ws_size,
                              hipStream_t stream) {
  const float* x  = (const float*)d_in[0];
  const int*   ei = (const int*)d_in[1];
  const float* ew = (const float*)d_in[2];
  const float* W1 = (const float*)d_in[3];
  const float* b1 = (const float*)d_in[4];
  const float* W2 = (const float*)d_in[5];
  const float* b2 = (const float*)d_in[6];
  const float* W3 = (const float*)d_in[7];
  const float* b3 = (const float*)d_in[8];
  int N = in_sizes[0] / NFEAT;
  int E = in_sizes[2];
  int M = E + N;
  const int* srcp = ei;
  const int* dstp = ei + E;

  char* p = (char*)d_ws;
  auto carve = [&](size_t bytes) -> void* {
    void* r = (void*)p;
    p += (bytes + 511) & ~(size_t)511;
    return r;
  };
  unsigned long long* packed = (unsigned long long*)carve(sizeof(unsigned long long) * N);
  int*     off    = (int*)  carve(sizeof(int) * E);
  int*     rowptr = (int*)  carve(sizeof(int) * (N + 1));
  float*   dis    = (float*)carve(sizeof(float) * N);
  int*     bsum   = (int*)  carve(sizeof(int) * 1024);
  EdgeRec* ep     = (EdgeRec*)carve(sizeof(EdgeRec) * M);
  float*   t1     = (float*)carve(sizeof(float) * (size_t)N * NFEAT);
  float*   t2     = (float*)carve(sizeof(float) * (size_t)N * NFEAT);
  float*   z      = (float*)carve(sizeof(float) * N);

  int gN = (N + 255) / 256, gE = (E + 255) / 256;
  int SB = (N + 1023) / 1024;

  k_init<<<gN, 256, 0, stream>>>(packed, N);
  k_count64<<<gE, 256, 0, stream>>>(dstp, ew, packed, off, E);
  k_dis<<<gN, 256, 0, stream>>>(packed, dis, N);
  k_scan1<<<SB, 256, 0, stream>>>(packed, bsum, N);
  k_scan2<<<1, 1024, 0, stream>>>(bsum, SB);
  k_scan3<<<SB, 256, 0, stream>>>(packed, bsum, rowptr, N, M);
  k_selfloop<<<gN, 256, 0, stream>>>(rowptr, dis, ep, N);
  k_fill<<<gE, 256, 0, stream>>>(srcp, dstp, ew, dis, rowptr, off, ep, E);

  int numTiles = (N + 63) / 64;   // 64 rows per block-tile (8 waves x 8 rows)
  int gg = 512;                   // 2 blocks/CU, persistent
  int gW = (N + 3) / 4;

  k_gemm128<<<gg, 512, 0, stream>>>(x, W1, t1, N, numTiles);
  k_agg128<<<gW, 256, 0, stream>>>(t1, rowptr, ep, dis, b1, t2, N);
  k_gemm128<<<gg, 512, 0, stream>>>(t2, W2, t1, N, numTiles);
  k_agg_final<<<gW, 256, 0, stream>>>(t1, rowptr, ep, dis, b2, W3, z, N);
  k_aggs<<<gN, 256, 0, stream>>>(z, rowptr, ep, dis, b3, (float*)d_out, N);
}